// Round 2
// baseline (409.592 us; speedup 1.0000x reference)
//
#include <hip/hip_runtime.h>
#include <hip/hip_bf16.h>
#include <hip/hip_fp16.h>

// TargetNet: per-sample MLP 2048->1024->512->256->128->1 over 64 samples x 256 spatial.
// Strategy: activations kept as f16 [B, 256(s), C] (spatial-major) so MFMA A (weights,
// row-major K-contig) and B (activations, K-contig per spatial col) both load contiguous
// 16B fragments. Weights fp32 streamed global->VGPR->cvt f16 exactly once (wave owns its
// 32 output rows for ALL 256 cols). X chunks staged via global_load_lds (16B) into
// fragment-ready LDS, double buffered, one barrier per K-step.
// ws layout: bufA = ws+0 (64 MiB): xT, then h2, then h4. bufB = ws+64MiB (32 MiB): h1, then h3.
// Peak ws use: 100,663,296 bytes.

typedef __attribute__((ext_vector_type(4)))  float    f32x4;
typedef __attribute__((ext_vector_type(16))) float    f32x16;
typedef __attribute__((ext_vector_type(8)))  short    short8;
typedef __attribute__((ext_vector_type(4)))  short    short4v;
typedef __attribute__((ext_vector_type(8)))  _Float16 half8;

__device__ __forceinline__ unsigned short f2h_bits(float f) {
  return __builtin_bit_cast(unsigned short, (_Float16)f);
}
__device__ __forceinline__ float h2f(short h) {
  return (float)__builtin_bit_cast(_Float16, (unsigned short)h);
}

// ---- transpose + convert: x [64][2048][256] f32 -> xT [64][256][2048] f16 ----
__global__ __launch_bounds__(256) void transpose_cvt(const float* __restrict__ X,
                                                     short* __restrict__ XT) {
  __shared__ float tile[32][33];
  const int b  = blockIdx.z;
  const int c0 = blockIdx.x * 32, s0 = blockIdx.y * 32;
  const int tl = threadIdx.x & 31, tw = threadIdx.x >> 5;  // tw: 0..7
  const float* xp = X + ((size_t)b * 2048 + c0) * 256 + s0;
#pragma unroll
  for (int i = 0; i < 4; ++i) {
    const int c = tw * 4 + i;
    tile[c][tl] = xp[(size_t)c * 256 + tl];   // coalesced 128B rows
  }
  __syncthreads();
  short* op = XT + ((size_t)(b * 256 + s0)) * 2048 + c0;
#pragma unroll
  for (int i = 0; i < 4; ++i) {
    const int s = tw * 4 + i;
    op[(size_t)s * 2048 + tl] = (short)f2h_bits(tile[tl][s]);  // stride-33 LDS read: conflict-free
  }
}

// ---- per-sample GEMM layer with fused bias+sigmoid ----
// C[s, m] = sigmoid( sum_k W[m,k] * X[s,k] + bias[m] ), per sample b.
// Wave tile: 32 rows (m) x (256/NSPLIT) cols (s). mfma_f32_32x32x16_f16.
// A frag: lane l holds row (l&31), k = (l>>5)*8 + j   (8 f16 from global W, cvt from fp32)
// B frag: lane l holds col (l&31), k = (l>>5)*8 + j   (16B ds_read from frag-ready LDS)
// C frag: col = lane&31, row = (reg&3) + 8*(reg>>2) + 4*(lane>>5)
template <int M, int K, int WAVES, int NSPLIT>
__global__ __launch_bounds__(WAVES * 64, 2) void gemm_layer(
    const float* __restrict__ W, const float* __restrict__ bias,
    const short* __restrict__ Xin, short* __restrict__ Out) {
  constexpr int BK    = 32;
  constexpr int NT    = K / BK;
  constexpr int NCG   = 8 / NSPLIT;      // 32-wide col groups per block
  constexpr int TILES = NCG * 2;         // 1KB LDS tiles per K-chunk
  constexpr int BM    = WAVES * 32;
  constexpr int MT    = M / BM;
  constexpr int TPW   = TILES / WAVES;
  constexpr int NS    = 256 / NSPLIT;

  __shared__ __align__(16) short lds[2][TILES * 512];

  const int tid = threadIdx.x;
  const int w = tid >> 6, l = tid & 63;
  const int lr = l & 31;   // row (A) / col (B)
  const int lh = l >> 5;   // k-half-group

  const int per_b = MT * NSPLIT;
  const int b   = blockIdx.x / per_b;
  const int rem = blockIdx.x % per_b;
  const int mt  = rem / NSPLIT;
  const int ns  = rem % NSPLIT;
  const int m0  = mt * BM + w * 32;

  const float* Wb = W + ((size_t)b * M + m0) * K;
  const short* Xb = Xin + (size_t)b * 256 * K + (size_t)ns * NS * K;

  f32x16 acc[NCG] = {};

  auto stage = [&](int buf, int t) {
    const int k0 = t * BK;
#pragma unroll
    for (int i = 0; i < TPW; ++i) {
      const int T  = w * TPW + i;
      const int s  = ((T >> 1) << 5) + lr;
      const int kk = ((T & 1) << 4) + (lh << 3);
      const short* src = Xb + (size_t)s * K + k0 + kk;   // 16B per lane, per-lane addr
      __builtin_amdgcn_global_load_lds(
          (const __attribute__((address_space(1))) void*)src,
          (__attribute__((address_space(3))) void*)&lds[buf][T * 512],
          16, 0, 0);   // wave-uniform LDS base + lane*16 -> fragment-ready layout
    }
  };

  stage(0, 0);
  __syncthreads();

  int cur = 0;
  for (int t = 0; t < NT; ++t) {
    if (t + 1 < NT) stage(cur ^ 1, t + 1);   // prefetch next chunk (drained at barrier)
#pragma unroll
    for (int h = 0; h < 2; ++h) {
      const float* wp = Wb + (size_t)lr * K + t * BK + h * 16 + lh * 8;
      const f32x4 w0 = *(const f32x4*)wp;
      const f32x4 w1 = *(const f32x4*)(wp + 4);
      half8 af;
#pragma unroll
      for (int j = 0; j < 4; ++j) {
        af[j]     = (_Float16)w0[j];
        af[j + 4] = (_Float16)w1[j];
      }
#pragma unroll
      for (int cg = 0; cg < NCG; ++cg) {
        const short8 braw = *(const short8*)&lds[cur][(cg * 2 + h) * 512 + l * 8];
        const half8  bf   = __builtin_bit_cast(half8, braw);
        acc[cg] = __builtin_amdgcn_mfma_f32_32x32x16_f16(af, bf, acc[cg], 0, 0, 0);
      }
    }
    __syncthreads();
    cur ^= 1;
  }

  // epilogue: bias + sigmoid + f16 store to Out[b][s][m]
  float brow[16];
#pragma unroll
  for (int r = 0; r < 16; ++r) {
    const int row = (r & 3) + 8 * (r >> 2) + (lh << 2);
    brow[r] = bias[(size_t)b * M + m0 + row];
  }
#pragma unroll
  for (int cg = 0; cg < NCG; ++cg) {
    const int s = ns * NS + cg * 32 + lr;
    short* op = Out + ((size_t)b * 256 + s) * M + m0;
#pragma unroll
    for (int rg = 0; rg < 4; ++rg) {
      short4v pk;
#pragma unroll
      for (int j = 0; j < 4; ++j) {
        const int r = rg * 4 + j;
        float v = acc[cg][r] + brow[r];
        v = 1.0f / (1.0f + __expf(-v));
        pk[j] = (short)f2h_bits(v);
      }
      *(short4v*)(op + rg * 8 + (lh << 2)) = pk;   // 8B store, 4 consecutive m
    }
  }
}

// ---- fc5: out[b,s] = sigmoid( dot(w5[b,:], h4[b,s,:]) + b5[b] ), K=128, fp32 out ----
__global__ __launch_bounds__(256) void fc5_sig(const float* __restrict__ W5,
                                               const float* __restrict__ B5,
                                               const short* __restrict__ H4,
                                               float* __restrict__ out) {
  const int tid = blockIdx.x * 256 + threadIdx.x;
  const int oi = tid >> 3;       // output index: b*256 + s
  const int r  = tid & 7;        // 8 lanes cooperate per output
  const int b  = oi >> 8;
  const short* hp = H4 + ((size_t)oi << 7) + r * 16;
  const float* wp = W5 + b * 128 + r * 16;
  const short8 hh0 = *(const short8*)hp;
  const short8 hh1 = *(const short8*)(hp + 8);
  const f32x4 w0 = *(const f32x4*)wp;
  const f32x4 w1 = *(const f32x4*)(wp + 4);
  const f32x4 w2 = *(const f32x4*)(wp + 8);
  const f32x4 w3 = *(const f32x4*)(wp + 12);
  float a = 0.f;
#pragma unroll
  for (int j = 0; j < 4; ++j) a += h2f(hh0[j]) * w0[j];
#pragma unroll
  for (int j = 0; j < 4; ++j) a += h2f(hh0[j + 4]) * w1[j];
#pragma unroll
  for (int j = 0; j < 4; ++j) a += h2f(hh1[j]) * w2[j];
#pragma unroll
  for (int j = 0; j < 4; ++j) a += h2f(hh1[j + 4]) * w3[j];
  a += __shfl_xor(a, 1);
  a += __shfl_xor(a, 2);
  a += __shfl_xor(a, 4);
  if (r == 0) out[oi] = 1.0f / (1.0f + __expf(-(a + B5[b])));
}

extern "C" void kernel_launch(void* const* d_in, const int* in_sizes, int n_in,
                              void* d_out, int out_size, void* d_ws, size_t ws_size,
                              hipStream_t stream) {
  const float* x  = (const float*)d_in[0];
  const float* w1 = (const float*)d_in[1];  const float* b1 = (const float*)d_in[2];
  const float* w2 = (const float*)d_in[3];  const float* b2 = (const float*)d_in[4];
  const float* w3 = (const float*)d_in[5];  const float* b3 = (const float*)d_in[6];
  const float* w4 = (const float*)d_in[7];  const float* b4 = (const float*)d_in[8];
  const float* w5 = (const float*)d_in[9];  const float* b5 = (const float*)d_in[10];

  char* ws = (char*)d_ws;
  short* bufA = (short*)ws;                            // 64 MiB region: xT, then h2, then h4
  short* bufB = (short*)(ws + (size_t)67108864);       // 32 MiB region: h1, then h3
  float* out  = (float*)d_out;

  // x -> xT (f16, [B,256,2048])
  transpose_cvt<<<dim3(64, 8, 64), 256, 0, stream>>>(x, bufA);
  // L1: 1024x2048, 4-wave blocks (BM=128), full-N blocks; 512 blocks
  gemm_layer<1024, 2048, 4, 1><<<512, 256, 0, stream>>>(w1, b1, bufA, bufB);  // h1 -> bufB
  // L2: 512x1024, 2-wave blocks (BM=64); 512 blocks
  gemm_layer<512, 1024, 2, 1><<<512, 128, 0, stream>>>(w2, b2, bufB, bufA);   // h2 -> bufA
  // L3: 256x512, 2-wave blocks, N split in 2; 512 blocks
  gemm_layer<256, 512, 2, 2><<<512, 128, 0, stream>>>(w3, b3, bufA, bufB);    // h3 -> bufB
  // L4: 128x256, 1-wave blocks, N split in 2; 512 blocks
  gemm_layer<128, 256, 1, 2><<<512, 64, 0, stream>>>(w4, b4, bufB, bufA);     // h4 -> bufA
  // L5 + final sigmoid, fp32 out [64,16,16]
  fc5_sig<<<512, 256, 0, stream>>>(w5, b5, bufA, out);
}

// Round 3
// 377.474 us; speedup vs baseline: 1.0851x; 1.0851x over previous
//
#include <hip/hip_runtime.h>
#include <hip/hip_bf16.h>
#include <hip/hip_fp16.h>

// TargetNet: per-sample MLP 2048->1024->512->256->128->1 over 64 samples x 256 spatial.
// R3 change: W-register double-buffer (prefetch W(t+1) before the barrier so HBM latency
// hides under MFMA of step t). Everything else unchanged from R2 baseline (409.6 us).

typedef __attribute__((ext_vector_type(4)))  float    f32x4;
typedef __attribute__((ext_vector_type(16))) float    f32x16;
typedef __attribute__((ext_vector_type(8)))  short    short8;
typedef __attribute__((ext_vector_type(4)))  short    short4v;
typedef __attribute__((ext_vector_type(8)))  _Float16 half8;

__device__ __forceinline__ unsigned short f2h_bits(float f) {
  return __builtin_bit_cast(unsigned short, (_Float16)f);
}
__device__ __forceinline__ float h2f(short h) {
  return (float)__builtin_bit_cast(_Float16, (unsigned short)h);
}

// ---- transpose + convert: x [64][2048][256] f32 -> xT [64][256][2048] f16 ----
__global__ __launch_bounds__(256) void transpose_cvt(const float* __restrict__ X,
                                                     short* __restrict__ XT) {
  __shared__ float tile[32][33];
  const int b  = blockIdx.z;
  const int c0 = blockIdx.x * 32, s0 = blockIdx.y * 32;
  const int tl = threadIdx.x & 31, tw = threadIdx.x >> 5;  // tw: 0..7
  const float* xp = X + ((size_t)b * 2048 + c0) * 256 + s0;
#pragma unroll
  for (int i = 0; i < 4; ++i) {
    const int c = tw * 4 + i;
    tile[c][tl] = xp[(size_t)c * 256 + tl];   // coalesced 128B rows
  }
  __syncthreads();
  short* op = XT + ((size_t)(b * 256 + s0)) * 2048 + c0;
#pragma unroll
  for (int i = 0; i < 4; ++i) {
    const int s = tw * 4 + i;
    op[(size_t)s * 2048 + tl] = (short)f2h_bits(tile[tl][s]);  // stride-33 LDS read: conflict-free
  }
}

// ---- per-sample GEMM layer with fused bias+sigmoid ----
// C[s, m] = sigmoid( sum_k W[m,k] * X[s,k] + bias[m] ), per sample b.
// Wave tile: 32 rows (m) x (256/NSPLIT) cols (s). mfma_f32_32x32x16_f16.
// A frag: lane l holds row (l&31), k = (l>>5)*8 + j   (8 f16 cvt from fp32 W, streamed once)
// B frag: lane l holds col (l&31), k = (l>>5)*8 + j   (16B ds_read from frag-ready LDS)
// C frag: col = lane&31, row = (reg&3) + 8*(reg>>2) + 4*(lane>>5)
struct WFrag { f32x4 a0, a1, b0, b1; };  // h=0 -> a0,a1 ; h=1 -> b0,b1 (16 floats/lane)

template <int M, int K, int WAVES, int NSPLIT>
__global__ __launch_bounds__(WAVES * 64, 2) void gemm_layer(
    const float* __restrict__ W, const float* __restrict__ bias,
    const short* __restrict__ Xin, short* __restrict__ Out) {
  constexpr int BK    = 32;
  constexpr int NT    = K / BK;
  constexpr int NCG   = 8 / NSPLIT;      // 32-wide col groups per block
  constexpr int TILES = NCG * 2;         // 1KB LDS tiles per K-chunk
  constexpr int BM    = WAVES * 32;
  constexpr int MT    = M / BM;
  constexpr int TPW   = TILES / WAVES;
  constexpr int NS    = 256 / NSPLIT;

  __shared__ __align__(16) short lds[2][TILES * 512];

  const int tid = threadIdx.x;
  const int w = tid >> 6, l = tid & 63;
  const int lr = l & 31;   // row (A) / col (B)
  const int lh = l >> 5;   // k-half-group

  const int per_b = MT * NSPLIT;
  const int b   = blockIdx.x / per_b;
  const int rem = blockIdx.x % per_b;
  const int mt  = rem / NSPLIT;
  const int ns  = rem % NSPLIT;
  const int m0  = mt * BM + w * 32;

  const float* Wb = W + ((size_t)b * M + m0) * K;
  const short* Xb = Xin + (size_t)b * 256 * K + (size_t)ns * NS * K;

  f32x16 acc[NCG] = {};

  auto stage = [&](int buf, int t) {
    const int k0 = t * BK;
#pragma unroll
    for (int i = 0; i < TPW; ++i) {
      const int T  = w * TPW + i;
      const int s  = ((T >> 1) << 5) + lr;
      const int kk = ((T & 1) << 4) + (lh << 3);
      const short* src = Xb + (size_t)s * K + k0 + kk;   // 16B per lane, per-lane addr
      __builtin_amdgcn_global_load_lds(
          (const __attribute__((address_space(1))) void*)src,
          (__attribute__((address_space(3))) void*)&lds[buf][T * 512],
          16, 0, 0);   // wave-uniform LDS base + lane*16 -> fragment-ready layout
    }
  };

  const float* wrow = Wb + (size_t)lr * K + (lh << 3);
  auto load_wfrag = [&](int t) {
    const float* wp = wrow + t * BK;
    WFrag f;
    f.a0 = *(const f32x4*)wp;        f.a1 = *(const f32x4*)(wp + 4);
    f.b0 = *(const f32x4*)(wp + 16); f.b1 = *(const f32x4*)(wp + 20);
    return f;
  };

  WFrag wc = load_wfrag(0);   // prologue: W regs for t=0
  stage(0, 0);
  __syncthreads();

  int cur = 0;
  for (int t = 0; t < NT; ++t) {
    if (t + 1 < NT) stage(cur ^ 1, t + 1);   // LDS prefetch next K-chunk
    WFrag wn;
    if (t + 1 < NT) wn = load_wfrag(t + 1);  // W reg prefetch: latency hides under MFMA below
    // h = 0
    {
      half8 af;
#pragma unroll
      for (int j = 0; j < 4; ++j) { af[j] = (_Float16)wc.a0[j]; af[j + 4] = (_Float16)wc.a1[j]; }
#pragma unroll
      for (int cg = 0; cg < NCG; ++cg) {
        const short8 braw = *(const short8*)&lds[cur][(cg * 2 + 0) * 512 + l * 8];
        acc[cg] = __builtin_amdgcn_mfma_f32_32x32x16_f16(af, __builtin_bit_cast(half8, braw),
                                                         acc[cg], 0, 0, 0);
      }
    }
    // h = 1
    {
      half8 af;
#pragma unroll
      for (int j = 0; j < 4; ++j) { af[j] = (_Float16)wc.b0[j]; af[j + 4] = (_Float16)wc.b1[j]; }
#pragma unroll
      for (int cg = 0; cg < NCG; ++cg) {
        const short8 braw = *(const short8*)&lds[cur][(cg * 2 + 1) * 512 + l * 8];
        acc[cg] = __builtin_amdgcn_mfma_f32_32x32x16_f16(af, __builtin_bit_cast(half8, braw),
                                                         acc[cg], 0, 0, 0);
      }
    }
    __syncthreads();          // drains staging AND wn loads (vmcnt(0)) - both needed next iter
    if (t + 1 < NT) wc = wn;  // register rename/copy, no scratch (static flow)
    cur ^= 1;
  }

  // epilogue: bias + sigmoid + f16 store to Out[b][s][m]
  float brow[16];
#pragma unroll
  for (int r = 0; r < 16; ++r) {
    const int row = (r & 3) + 8 * (r >> 2) + (lh << 2);
    brow[r] = bias[(size_t)b * M + m0 + row];
  }
#pragma unroll
  for (int cg = 0; cg < NCG; ++cg) {
    const int s = ns * NS + cg * 32 + lr;
    short* op = Out + ((size_t)b * 256 + s) * M + m0;
#pragma unroll
    for (int rg = 0; rg < 4; ++rg) {
      short4v pk;
#pragma unroll
      for (int j = 0; j < 4; ++j) {
        const int r = rg * 4 + j;
        float v = acc[cg][r] + brow[r];
        v = 1.0f / (1.0f + __expf(-v));
        pk[j] = (short)f2h_bits(v);
      }
      *(short4v*)(op + rg * 8 + (lh << 2)) = pk;   // 8B store, 4 consecutive m
    }
  }
}

// ---- fc5: out[b,s] = sigmoid( dot(w5[b,:], h4[b,s,:]) + b5[b] ), K=128, fp32 out ----
__global__ __launch_bounds__(256) void fc5_sig(const float* __restrict__ W5,
                                               const float* __restrict__ B5,
                                               const short* __restrict__ H4,
                                               float* __restrict__ out) {
  const int tid = blockIdx.x * 256 + threadIdx.x;
  const int oi = tid >> 3;       // output index: b*256 + s
  const int r  = tid & 7;        // 8 lanes cooperate per output
  const int b  = oi >> 8;
  const short* hp = H4 + ((size_t)oi << 7) + r * 16;
  const float* wp = W5 + b * 128 + r * 16;
  const short8 hh0 = *(const short8*)hp;
  const short8 hh1 = *(const short8*)(hp + 8);
  const f32x4 w0 = *(const f32x4*)wp;
  const f32x4 w1 = *(const f32x4*)(wp + 4);
  const f32x4 w2 = *(const f32x4*)(wp + 8);
  const f32x4 w3 = *(const f32x4*)(wp + 12);
  float a = 0.f;
#pragma unroll
  for (int j = 0; j < 4; ++j) a += h2f(hh0[j]) * w0[j];
#pragma unroll
  for (int j = 0; j < 4; ++j) a += h2f(hh0[j + 4]) * w1[j];
#pragma unroll
  for (int j = 0; j < 4; ++j) a += h2f(hh1[j]) * w2[j];
#pragma unroll
  for (int j = 0; j < 4; ++j) a += h2f(hh1[j + 4]) * w3[j];
  a += __shfl_xor(a, 1);
  a += __shfl_xor(a, 2);
  a += __shfl_xor(a, 4);
  if (r == 0) out[oi] = 1.0f / (1.0f + __expf(-(a + B5[b])));
}

extern "C" void kernel_launch(void* const* d_in, const int* in_sizes, int n_in,
                              void* d_out, int out_size, void* d_ws, size_t ws_size,
                              hipStream_t stream) {
  const float* x  = (const float*)d_in[0];
  const float* w1 = (const float*)d_in[1];  const float* b1 = (const float*)d_in[2];
  const float* w2 = (const float*)d_in[3];  const float* b2 = (const float*)d_in[4];
  const float* w3 = (const float*)d_in[5];  const float* b3 = (const float*)d_in[6];
  const float* w4 = (const float*)d_in[7];  const float* b4 = (const float*)d_in[8];
  const float* w5 = (const float*)d_in[9];  const float* b5 = (const float*)d_in[10];

  char* ws = (char*)d_ws;
  short* bufA = (short*)ws;                            // 64 MiB region: xT, then h2, then h4
  short* bufB = (short*)(ws + (size_t)67108864);       // 32 MiB region: h1, then h3
  float* out  = (float*)d_out;

  // x -> xT (f16, [B,256,2048])
  transpose_cvt<<<dim3(64, 8, 64), 256, 0, stream>>>(x, bufA);
  // L1: 1024x2048, 4-wave blocks (BM=128), full-N blocks; 512 blocks
  gemm_layer<1024, 2048, 4, 1><<<512, 256, 0, stream>>>(w1, b1, bufA, bufB);  // h1 -> bufB
  // L2: 512x1024, 2-wave blocks (BM=64); 512 blocks
  gemm_layer<512, 1024, 2, 1><<<512, 128, 0, stream>>>(w2, b2, bufB, bufA);   // h2 -> bufA
  // L3: 256x512, 2-wave blocks, N split in 2; 512 blocks
  gemm_layer<256, 512, 2, 2><<<512, 128, 0, stream>>>(w3, b3, bufA, bufB);    // h3 -> bufB
  // L4: 128x256, 1-wave blocks, N split in 2; 512 blocks
  gemm_layer<128, 256, 1, 2><<<512, 64, 0, stream>>>(w4, b4, bufB, bufA);     // h4 -> bufA
  // L5 + final sigmoid, fp32 out [64,16,16]
  fc5_sig<<<512, 256, 0, stream>>>(w5, b5, bufA, out);
}

// Round 4
// 345.050 us; speedup vs baseline: 1.1871x; 1.0940x over previous
//
#include <hip/hip_runtime.h>
#include <hip/hip_bf16.h>
#include <hip/hip_fp16.h>

// TargetNet: per-sample MLP 2048->1024->512->256->128->1 over 64 samples x 256 spatial.
// R4 changes vs R3 (377.5 us):
//  (a) BK 32->64: 256B per W-row per iteration (DRAM row locality), half the barrier drains.
//  (b) Epilogue per-wave 32x32 LDS transpose -> fully dense 64B-aligned global stores
//      (was 8B per lane scattered at 2KB stride = heavy TCC write-sector inflation).

typedef __attribute__((ext_vector_type(4)))  float    f32x4;
typedef __attribute__((ext_vector_type(16))) float    f32x16;
typedef __attribute__((ext_vector_type(8)))  short    short8;
typedef __attribute__((ext_vector_type(4)))  short    short4v;
typedef __attribute__((ext_vector_type(8)))  _Float16 half8;

__device__ __forceinline__ unsigned short f2h_bits(float f) {
  return __builtin_bit_cast(unsigned short, (_Float16)f);
}
__device__ __forceinline__ float h2f(short h) {
  return (float)__builtin_bit_cast(_Float16, (unsigned short)h);
}

// ---- transpose + convert: x [64][2048][256] f32 -> xT [64][256][2048] f16 ----
__global__ __launch_bounds__(256) void transpose_cvt(const float* __restrict__ X,
                                                     short* __restrict__ XT) {
  __shared__ float tile[32][33];
  const int b  = blockIdx.z;
  const int c0 = blockIdx.x * 32, s0 = blockIdx.y * 32;
  const int tl = threadIdx.x & 31, tw = threadIdx.x >> 5;  // tw: 0..7
  const float* xp = X + ((size_t)b * 2048 + c0) * 256 + s0;
#pragma unroll
  for (int i = 0; i < 4; ++i) {
    const int c = tw * 4 + i;
    tile[c][tl] = xp[(size_t)c * 256 + tl];   // coalesced 128B rows
  }
  __syncthreads();
  short* op = XT + ((size_t)(b * 256 + s0)) * 2048 + c0;
#pragma unroll
  for (int i = 0; i < 4; ++i) {
    const int s = tw * 4 + i;
    op[(size_t)s * 2048 + tl] = (short)f2h_bits(tile[tl][s]);  // stride-33 LDS read: conflict-free
  }
}

// ---- per-sample GEMM layer with fused bias+sigmoid ----
// C[s, m] = sigmoid( sum_k W[m,k] * X[s,k] + bias[m] ), per sample b.
// Wave tile: 32 rows (m) x (256/NSPLIT) cols (s). mfma_f32_32x32x16_f16.
// A frag: lane l holds row (l&31), k = (l>>5)*8 + j   (f16 cvt from fp32 W, streamed once)
// B frag: lane l holds col (l&31), k = (l>>5)*8 + j   (16B ds_read from frag-ready LDS)
// C frag: col = lane&31, row = (reg&3) + 8*(reg>>2) + 4*(lane>>5)
struct WFrag { f32x4 v[8]; };  // 32 floats/lane = one 64-wide K-step of this lane's W row

template <int M, int K, int WAVES, int NSPLIT>
__global__ __launch_bounds__(WAVES * 64, 2) void gemm_layer(
    const float* __restrict__ W, const float* __restrict__ bias,
    const short* __restrict__ Xin, short* __restrict__ Out) {
  constexpr int BK    = 64;
  constexpr int KH    = BK / 16;         // 4 k-quarters per K-step
  constexpr int NT    = K / BK;
  constexpr int NCG   = 8 / NSPLIT;      // 32-wide col groups per block
  constexpr int TILES = NCG * KH;        // 1KB LDS tiles per K-chunk
  constexpr int BM    = WAVES * 32;
  constexpr int MT    = M / BM;
  constexpr int TPW   = TILES / WAVES;
  constexpr int NS    = 256 / NSPLIT;
  constexpr int EPIW  = 40;              // 80B rows: 8B/16B aligned, modest bank aliasing

  __shared__ __align__(16) short lds[2][TILES * 512];
  __shared__ __align__(16) short epi[WAVES][32][EPIW];

  const int tid = threadIdx.x;
  const int w = tid >> 6, l = tid & 63;
  const int lr = l & 31;   // row (A) / col (B)
  const int lh = l >> 5;   // k-half-group

  const int per_b = MT * NSPLIT;
  const int b   = blockIdx.x / per_b;
  const int rem = blockIdx.x % per_b;
  const int mt  = rem / NSPLIT;
  const int ns  = rem % NSPLIT;
  const int m0  = mt * BM + w * 32;

  const float* Wb = W + ((size_t)b * M + m0) * K;
  const short* Xb = Xin + (size_t)b * 256 * K + (size_t)ns * NS * K;

  f32x16 acc[NCG] = {};

  auto stage = [&](int buf, int t) {
    const int k0 = t * BK;
#pragma unroll
    for (int i = 0; i < TPW; ++i) {
      const int T  = w * TPW + i;
      const int s  = (T / KH) * 32 + lr;
      const int kk = (T % KH) * 16 + (lh << 3);
      const short* src = Xb + (size_t)s * K + k0 + kk;   // 16B per lane, per-lane addr
      __builtin_amdgcn_global_load_lds(
          (const __attribute__((address_space(1))) void*)src,
          (__attribute__((address_space(3))) void*)&lds[buf][T * 512],
          16, 0, 0);   // wave-uniform LDS base + lane*16 -> fragment-ready layout
    }
  };

  const float* wrow = Wb + (size_t)lr * K + (lh << 3);
  auto load_wfrag = [&](int t) {
    WFrag f;
#pragma unroll
    for (int h = 0; h < KH; ++h) {
      const float* wp = wrow + t * BK + h * 16;
      f.v[2 * h]     = *(const f32x4*)wp;
      f.v[2 * h + 1] = *(const f32x4*)(wp + 4);
    }
    return f;
  };

  WFrag wc = load_wfrag(0);   // prologue W regs for t=0
  stage(0, 0);
  __syncthreads();

  int cur = 0;
  for (int t = 0; t < NT; ++t) {
    WFrag wn;
    if (t + 1 < NT) wn = load_wfrag(t + 1);  // issue HBM-critical W first
    if (t + 1 < NT) stage(cur ^ 1, t + 1);   // then LDS prefetch next X chunk
#pragma unroll
    for (int h = 0; h < KH; ++h) {
      half8 af;
#pragma unroll
      for (int j = 0; j < 4; ++j) {
        af[j]     = (_Float16)wc.v[2 * h][j];
        af[j + 4] = (_Float16)wc.v[2 * h + 1][j];
      }
#pragma unroll
      for (int cg = 0; cg < NCG; ++cg) {
        const short8 braw = *(const short8*)&lds[cur][(cg * KH + h) * 512 + l * 8];
        acc[cg] = __builtin_amdgcn_mfma_f32_32x32x16_f16(af, __builtin_bit_cast(half8, braw),
                                                         acc[cg], 0, 0, 0);
      }
    }
    __syncthreads();          // drains staging AND wn loads - both needed next iter
    if (t + 1 < NT) wc = wn;  // static register flow, no scratch
    cur ^= 1;
  }

  // epilogue: bias + sigmoid, per-wave 32x32 LDS transpose, dense 16B stores
  float brow[16];
#pragma unroll
  for (int r = 0; r < 16; ++r) {
    const int row = (r & 3) + 8 * (r >> 2) + (lh << 2);
    brow[r] = bias[(size_t)b * M + m0 + row];
  }
  const int s_loc = l >> 1, hi = l & 1;
#pragma unroll
  for (int cg = 0; cg < NCG; ++cg) {
    // write phase: lane l owns col s=lr; 4 consecutive m per 8B LDS write
#pragma unroll
    for (int rg = 0; rg < 4; ++rg) {
      short4v pk;
#pragma unroll
      for (int j = 0; j < 4; ++j) {
        const int r = rg * 4 + j;
        float v = acc[cg][r] + brow[r];
        v = 1.0f / (1.0f + __expf(-v));
        pk[j] = (short)f2h_bits(v);
      }
      *(short4v*)&epi[w][lr][rg * 8 + (lh << 2)] = pk;
    }
    // read phase (same-wave, DS in-order + compiler alias waits; wave-private buffer)
    const short8 r0 = *(const short8*)&epi[w][s_loc][hi * 16];
    const short8 r1 = *(const short8*)&epi[w][s_loc][hi * 16 + 8];
    short* op = Out + ((size_t)b * 256 + ns * NS + cg * 32 + s_loc) * M + m0 + hi * 16;
    *(short8*)op       = r0;   // 16B store; lane-pairs form dense 64B segments
    *(short8*)(op + 8) = r1;
  }
}

// ---- fc5: out[b,s] = sigmoid( dot(w5[b,:], h4[b,s,:]) + b5[b] ), K=128, fp32 out ----
__global__ __launch_bounds__(256) void fc5_sig(const float* __restrict__ W5,
                                               const float* __restrict__ B5,
                                               const short* __restrict__ H4,
                                               float* __restrict__ out) {
  const int tid = blockIdx.x * 256 + threadIdx.x;
  const int oi = tid >> 3;       // output index: b*256 + s
  const int r  = tid & 7;        // 8 lanes cooperate per output
  const int b  = oi >> 8;
  const short* hp = H4 + ((size_t)oi << 7) + r * 16;
  const float* wp = W5 + b * 128 + r * 16;
  const short8 hh0 = *(const short8*)hp;
  const short8 hh1 = *(const short8*)(hp + 8);
  const f32x4 w0 = *(const f32x4*)wp;
  const f32x4 w1 = *(const f32x4*)(wp + 4);
  const f32x4 w2 = *(const f32x4*)(wp + 8);
  const f32x4 w3 = *(const f32x4*)(wp + 12);
  float a = 0.f;
#pragma unroll
  for (int j = 0; j < 4; ++j) a += h2f(hh0[j]) * w0[j];
#pragma unroll
  for (int j = 0; j < 4; ++j) a += h2f(hh0[j + 4]) * w1[j];
#pragma unroll
  for (int j = 0; j < 4; ++j) a += h2f(hh1[j]) * w2[j];
#pragma unroll
  for (int j = 0; j < 4; ++j) a += h2f(hh1[j + 4]) * w3[j];
  a += __shfl_xor(a, 1);
  a += __shfl_xor(a, 2);
  a += __shfl_xor(a, 4);
  if (r == 0) out[oi] = 1.0f / (1.0f + __expf(-(a + B5[b])));
}

extern "C" void kernel_launch(void* const* d_in, const int* in_sizes, int n_in,
                              void* d_out, int out_size, void* d_ws, size_t ws_size,
                              hipStream_t stream) {
  const float* x  = (const float*)d_in[0];
  const float* w1 = (const float*)d_in[1];  const float* b1 = (const float*)d_in[2];
  const float* w2 = (const float*)d_in[3];  const float* b2 = (const float*)d_in[4];
  const float* w3 = (const float*)d_in[5];  const float* b3 = (const float*)d_in[6];
  const float* w4 = (const float*)d_in[7];  const float* b4 = (const float*)d_in[8];
  const float* w5 = (const float*)d_in[9];  const float* b5 = (const float*)d_in[10];

  char* ws = (char*)d_ws;
  short* bufA = (short*)ws;                            // 64 MiB region: xT, then h2, then h4
  short* bufB = (short*)(ws + (size_t)67108864);       // 32 MiB region: h1, then h3
  float* out  = (float*)d_out;

  // x -> xT (f16, [B,256,2048])
  transpose_cvt<<<dim3(64, 8, 64), 256, 0, stream>>>(x, bufA);
  // L1: 1024x2048, 4-wave blocks (BM=128), full-N blocks; 512 blocks
  gemm_layer<1024, 2048, 4, 1><<<512, 256, 0, stream>>>(w1, b1, bufA, bufB);  // h1 -> bufB
  // L2: 512x1024, 2-wave blocks (BM=64); 512 blocks
  gemm_layer<512, 1024, 2, 1><<<512, 128, 0, stream>>>(w2, b2, bufB, bufA);   // h2 -> bufA
  // L3: 256x512, 2-wave blocks, N split in 2; 512 blocks
  gemm_layer<256, 512, 2, 2><<<512, 128, 0, stream>>>(w3, b3, bufA, bufB);    // h3 -> bufB
  // L4: 128x256, 1-wave blocks, N split in 2; 512 blocks
  gemm_layer<128, 256, 1, 2><<<512, 64, 0, stream>>>(w4, b4, bufB, bufA);     // h4 -> bufA
  // L5 + final sigmoid, fp32 out [64,16,16]
  fc5_sig<<<512, 256, 0, stream>>>(w5, b5, bufA, out);
}

// Round 5
// 340.939 us; speedup vs baseline: 1.2014x; 1.0121x over previous
//
#include <hip/hip_runtime.h>
#include <hip/hip_bf16.h>
#include <hip/hip_fp16.h>

// TargetNet: per-sample MLP 2048->1024->512->256->128->1 over 64 samples x 256 spatial.
// R5 change vs R4 (345.0 us): counted-vmcnt software pipeline (T3/T4) in gemm_layer.
// Raw s_barrier + asm vmcnt(8) instead of __syncthreads()'s vmcnt(0) drain:
//   - stage(t+2) DMA issued right after the barrier (2-iter window)
//   - W(t+1) register loads stay in flight across the barrier; cvt waits exactly
// Issue order pinned with empty asm memory fences so vmcnt counts are deterministic
// (vmcnt retires in issue order, m135).

typedef __attribute__((ext_vector_type(4)))  float    f32x4;
typedef __attribute__((ext_vector_type(16))) float    f32x16;
typedef __attribute__((ext_vector_type(8)))  short    short8;
typedef __attribute__((ext_vector_type(4)))  short    short4v;
typedef __attribute__((ext_vector_type(8)))  _Float16 half8;

__device__ __forceinline__ unsigned short f2h_bits(float f) {
  return __builtin_bit_cast(unsigned short, (_Float16)f);
}
__device__ __forceinline__ float h2f(short h) {
  return (float)__builtin_bit_cast(_Float16, (unsigned short)h);
}

// ---- transpose + convert: x [64][2048][256] f32 -> xT [64][256][2048] f16 ----
__global__ __launch_bounds__(256) void transpose_cvt(const float* __restrict__ X,
                                                     short* __restrict__ XT) {
  __shared__ float tile[32][33];
  const int b  = blockIdx.z;
  const int c0 = blockIdx.x * 32, s0 = blockIdx.y * 32;
  const int tl = threadIdx.x & 31, tw = threadIdx.x >> 5;  // tw: 0..7
  const float* xp = X + ((size_t)b * 2048 + c0) * 256 + s0;
#pragma unroll
  for (int i = 0; i < 4; ++i) {
    const int c = tw * 4 + i;
    tile[c][tl] = xp[(size_t)c * 256 + tl];   // coalesced 128B rows
  }
  __syncthreads();
  short* op = XT + ((size_t)(b * 256 + s0)) * 2048 + c0;
#pragma unroll
  for (int i = 0; i < 4; ++i) {
    const int s = tw * 4 + i;
    op[(size_t)s * 2048 + tl] = (short)f2h_bits(tile[tl][s]);  // stride-33 LDS read: conflict-free
  }
}

// ---- per-sample GEMM layer with fused bias+sigmoid ----
// C[s, m] = sigmoid( sum_k W[m,k] * X[s,k] + bias[m] ), per sample b.
// Wave tile: 32 rows (m) x (256/NSPLIT) cols (s). mfma_f32_32x32x16_f16.
// A frag: lane l holds row (l&31), k = (l>>5)*8 + j   (f16 cvt from fp32 W, streamed once)
// B frag: lane l holds col (l&31), k = (l>>5)*8 + j   (16B ds_read from frag-ready LDS)
// C frag: col = lane&31, row = (reg&3) + 8*(reg>>2) + 4*(lane>>5)
struct WFrag { f32x4 v[8]; };  // 32 floats/lane = one 64-wide K-step of this lane's W row

template <int M, int K, int WAVES, int NSPLIT>
__global__ __launch_bounds__(WAVES * 64, 2) void gemm_layer(
    const float* __restrict__ W, const float* __restrict__ bias,
    const short* __restrict__ Xin, short* __restrict__ Out) {
  constexpr int BK    = 64;
  constexpr int KH    = BK / 16;         // 4 k-quarters per K-step
  constexpr int NT    = K / BK;
  constexpr int NCG   = 8 / NSPLIT;      // 32-wide col groups per block
  constexpr int TILES = NCG * KH;        // 1KB LDS tiles per K-chunk
  constexpr int BM    = WAVES * 32;
  constexpr int MT    = M / BM;
  constexpr int TPW   = TILES / WAVES;   // stage DMA ops per wave per K-step
  constexpr int NS    = 256 / NSPLIT;
  constexpr int EPIW  = 40;              // 80B rows: 8B/16B aligned, modest bank aliasing

  __shared__ __align__(16) short lds[2][TILES * 512];
  __shared__ __align__(16) short epi[WAVES][32][EPIW];

  const int tid = threadIdx.x;
  const int w = tid >> 6, l = tid & 63;
  const int lr = l & 31;   // row (A) / col (B)
  const int lh = l >> 5;   // k-half-group

  const int per_b = MT * NSPLIT;
  const int b   = blockIdx.x / per_b;
  const int rem = blockIdx.x % per_b;
  const int mt  = rem / NSPLIT;
  const int ns  = rem % NSPLIT;
  const int m0  = mt * BM + w * 32;

  const float* Wb = W + ((size_t)b * M + m0) * K;
  const short* Xb = Xin + (size_t)b * 256 * K + (size_t)ns * NS * K;

  f32x16 acc[NCG] = {};

  auto stage = [&](int buf, int t) {
    const int k0 = t * BK;
#pragma unroll
    for (int i = 0; i < TPW; ++i) {
      const int T  = w * TPW + i;
      const int s  = (T / KH) * 32 + lr;
      const int kk = (T % KH) * 16 + (lh << 3);
      const short* src = Xb + (size_t)s * K + k0 + kk;   // 16B per lane, per-lane addr
      __builtin_amdgcn_global_load_lds(
          (const __attribute__((address_space(1))) void*)src,
          (__attribute__((address_space(3))) void*)&lds[buf][T * 512],
          16, 0, 0);   // wave-uniform LDS base + lane*16 -> fragment-ready layout
    }
  };

  const float* wrow = Wb + (size_t)lr * K + (lh << 3);
  auto load_wfrag = [&](int t) {
    WFrag f;
#pragma unroll
    for (int h = 0; h < KH; ++h) {
      const float* wp = wrow + t * BK + h * 16;
      f.v[2 * h]     = *(const f32x4*)wp;
      f.v[2 * h + 1] = *(const f32x4*)(wp + 4);
    }
    return f;
  };

  WFrag wn;
  half8 wcH[KH];
  auto cvtW = [&]() {   // wn (fp32, compiler waits exact vmcnt) -> wcH (f16 MFMA A-frags)
#pragma unroll
    for (int h = 0; h < KH; ++h) {
#pragma unroll
      for (int j = 0; j < 4; ++j) {
        wcH[h][j]     = (_Float16)wn.v[2 * h][j];
        wcH[h][j + 4] = (_Float16)wn.v[2 * h + 1][j];
      }
    }
  };

  // ---- prologue: queue = [stage(0), W(0), stage(1)]; cvt W(0) (in-order retire
  //      implies stage(0) done too); issue W(1); barrier -> buf0 visible.
  stage(0, 0);
  asm volatile("" ::: "memory");
  wn = load_wfrag(0);
  asm volatile("" ::: "memory");
  stage(1, 1);
  asm volatile("" ::: "memory");
  cvtW();
  wn = load_wfrag(1);
  asm volatile("" ::: "memory");
  asm volatile("s_barrier" ::: "memory");
  __builtin_amdgcn_sched_barrier(0);

  // ---- main loop: never drain vmcnt to 0; stage(t+2)/W(t+2) span the barrier.
  for (int t = 0; t < NT; ++t) {
    const int cur = t & 1;
#pragma unroll
    for (int h = 0; h < KH; ++h) {
#pragma unroll
      for (int cg = 0; cg < NCG; ++cg) {
        const short8 braw = *(const short8*)&lds[cur][(cg * KH + h) * 512 + l * 8];
        acc[cg] = __builtin_amdgcn_mfma_f32_32x32x16_f16(wcH[h], __builtin_bit_cast(half8, braw),
                                                         acc[cg], 0, 0, 0);
      }
    }
    if (t + 1 < NT) {                      // uniform branch
      // queue: [stage(t+1) (TPW), W(t+1) (8)] -> vmcnt(8): stage(t+1) retired, W may fly
      asm volatile("s_waitcnt vmcnt(8)" ::: "memory");
      __builtin_amdgcn_sched_barrier(0);
      asm volatile("s_barrier" ::: "memory");   // all waves done reading buf[cur]
      __builtin_amdgcn_sched_barrier(0);
      if (t + 2 < NT) {
        stage(cur, t + 2);                 // refill the buffer just freed by the barrier
        asm volatile("" ::: "memory");
      }
      cvtW();                              // W(t+1): compiler-exact vmcnt wait
      if (t + 2 < NT) {
        wn = load_wfrag(t + 2);
        asm volatile("" ::: "memory");
      }
    }
  }

  // epilogue: bias + sigmoid, per-wave 32x32 LDS transpose, dense 16B stores
  float brow[16];
#pragma unroll
  for (int r = 0; r < 16; ++r) {
    const int row = (r & 3) + 8 * (r >> 2) + (lh << 2);
    brow[r] = bias[(size_t)b * M + m0 + row];
  }
  const int s_loc = l >> 1, hi = l & 1;
#pragma unroll
  for (int cg = 0; cg < NCG; ++cg) {
    // write phase: lane l owns col s=lr; 4 consecutive m per 8B LDS write
#pragma unroll
    for (int rg = 0; rg < 4; ++rg) {
      short4v pk;
#pragma unroll
      for (int j = 0; j < 4; ++j) {
        const int r = rg * 4 + j;
        float v = acc[cg][r] + brow[r];
        v = 1.0f / (1.0f + __expf(-v));
        pk[j] = (short)f2h_bits(v);
      }
      *(short4v*)&epi[w][lr][rg * 8 + (lh << 2)] = pk;
    }
    // read phase (same-wave, DS in-order + compiler alias waits; wave-private buffer)
    const short8 r0 = *(const short8*)&epi[w][s_loc][hi * 16];
    const short8 r1 = *(const short8*)&epi[w][s_loc][hi * 16 + 8];
    short* op = Out + ((size_t)b * 256 + ns * NS + cg * 32 + s_loc) * M + m0 + hi * 16;
    *(short8*)op       = r0;   // 16B store; lane-pairs form dense 64B segments
    *(short8*)(op + 8) = r1;
  }
}

// ---- fc5: out[b,s] = sigmoid( dot(w5[b,:], h4[b,s,:]) + b5[b] ), K=128, fp32 out ----
__global__ __launch_bounds__(256) void fc5_sig(const float* __restrict__ W5,
                                               const float* __restrict__ B5,
                                               const short* __restrict__ H4,
                                               float* __restrict__ out) {
  const int tid = blockIdx.x * 256 + threadIdx.x;
  const int oi = tid >> 3;       // output index: b*256 + s
  const int r  = tid & 7;        // 8 lanes cooperate per output
  const int b  = oi >> 8;
  const short* hp = H4 + ((size_t)oi << 7) + r * 16;
  const float* wp = W5 + b * 128 + r * 16;
  const short8 hh0 = *(const short8*)hp;
  const short8 hh1 = *(const short8*)(hp + 8);
  const f32x4 w0 = *(const f32x4*)wp;
  const f32x4 w1 = *(const f32x4*)(wp + 4);
  const f32x4 w2 = *(const f32x4*)(wp + 8);
  const f32x4 w3 = *(const f32x4*)(wp + 12);
  float a = 0.f;
#pragma unroll
  for (int j = 0; j < 4; ++j) a += h2f(hh0[j]) * w0[j];
#pragma unroll
  for (int j = 0; j < 4; ++j) a += h2f(hh0[j + 4]) * w1[j];
#pragma unroll
  for (int j = 0; j < 4; ++j) a += h2f(hh1[j]) * w2[j];
#pragma unroll
  for (int j = 0; j < 4; ++j) a += h2f(hh1[j + 4]) * w3[j];
  a += __shfl_xor(a, 1);
  a += __shfl_xor(a, 2);
  a += __shfl_xor(a, 4);
  if (r == 0) out[oi] = 1.0f / (1.0f + __expf(-(a + B5[b])));
}

extern "C" void kernel_launch(void* const* d_in, const int* in_sizes, int n_in,
                              void* d_out, int out_size, void* d_ws, size_t ws_size,
                              hipStream_t stream) {
  const float* x  = (const float*)d_in[0];
  const float* w1 = (const float*)d_in[1];  const float* b1 = (const float*)d_in[2];
  const float* w2 = (const float*)d_in[3];  const float* b2 = (const float*)d_in[4];
  const float* w3 = (const float*)d_in[5];  const float* b3 = (const float*)d_in[6];
  const float* w4 = (const float*)d_in[7];  const float* b4 = (const float*)d_in[8];
  const float* w5 = (const float*)d_in[9];  const float* b5 = (const float*)d_in[10];

  char* ws = (char*)d_ws;
  short* bufA = (short*)ws;                            // 64 MiB region: xT, then h2, then h4
  short* bufB = (short*)(ws + (size_t)67108864);       // 32 MiB region: h1, then h3
  float* out  = (float*)d_out;

  // x -> xT (f16, [B,256,2048])
  transpose_cvt<<<dim3(64, 8, 64), 256, 0, stream>>>(x, bufA);
  // L1: 1024x2048, 4-wave blocks (BM=128), full-N blocks; 512 blocks
  gemm_layer<1024, 2048, 4, 1><<<512, 256, 0, stream>>>(w1, b1, bufA, bufB);  // h1 -> bufB
  // L2: 512x1024, 2-wave blocks (BM=64); 512 blocks
  gemm_layer<512, 1024, 2, 1><<<512, 128, 0, stream>>>(w2, b2, bufB, bufA);   // h2 -> bufA
  // L3: 256x512, 2-wave blocks, N split in 2; 512 blocks
  gemm_layer<256, 512, 2, 2><<<512, 128, 0, stream>>>(w3, b3, bufA, bufB);    // h3 -> bufB
  // L4: 128x256, 1-wave blocks, N split in 2; 512 blocks
  gemm_layer<128, 256, 1, 2><<<512, 64, 0, stream>>>(w4, b4, bufB, bufA);     // h4 -> bufA
  // L5 + final sigmoid, fp32 out [64,16,16]
  fc5_sig<<<512, 256, 0, stream>>>(w5, b5, bufA, out);
}